// Round 8
// baseline (421.749 us; speedup 1.0000x reference)
//
#include <hip/hip_runtime.h>
#include <hip/hip_bf16.h>

#define N_NODES 20000
#define E_EDGES 320000
#define F_INN   64
#define HID     128
#define HEADS   2
#define HC      (HEADS * HID)   // 256
#define G_GR    64
#define MIDD    32
#define EPSV    1e-5f
#define NBUK    79              // ceil(20000/256); bucket = node >> 8

#define CDIV(a, b) (((a) + (b) - 1) / (b))

typedef __attribute__((ext_vector_type(8))) short          bf16x8;  // MFMA A/B frag
typedef __attribute__((ext_vector_type(4))) float          f32x4;   // MFMA C/D frag
typedef __attribute__((ext_vector_type(8))) unsigned short u16x8;

// ---------- bf16 helpers (RNE) ----------
__device__ inline float bf2f(unsigned short u) { return __uint_as_float((unsigned)u << 16); }
__device__ inline unsigned short f2bf(float f) {
    unsigned u = __float_as_uint(f);
    unsigned r = u + 0x7FFFu + ((u >> 16) & 1u);
    return (unsigned short)(r >> 16);
}

#if __has_builtin(__builtin_amdgcn_exp2f)
__device__ inline float fexp2(float x) { return __builtin_amdgcn_exp2f(x); }
#else
__device__ inline float fexp2(float x) { return exp2f(x); }
#endif

// ================= CSR construction (3 CSRs, bucket-granular two-pass) ========
// tmp entry packed: (key & 255) << 24 | payload   (payload < 2^24: edge id < 320k)
struct Csr3 {
    const int* key[3];
    const int* other[3];   // payload source for y=0,1; y=2 stores edge id
    int* btot;      // [3*NBUK] bucket totals (zeroed)
    int* bstart;    // [3*(NBUK+1)] bucket starts
    int* bcur;      // [3*NBUK] bucket cursors
    int* rowptr[3]; // [N+1] (written by bucketB)
    int* out[3];    // [E] payload (final, CSR order)
    int* tmp;       // [3*E] packed (key_local,payload) bucket-partitioned
};

__global__ __launch_bounds__(256) void k_bhist(Csr3 c) {
    __shared__ int hist[NBUK];
    const int y = blockIdx.y;
    const int chunk0 = blockIdx.x * 4096;
    const int t = threadIdx.x;
    for (int i = t; i < NBUK; i += 256) hist[i] = 0;
    __syncthreads();
#pragma unroll
    for (int i = 0; i < 16; i++) {
        int e = chunk0 + (i << 8) + t;
        if (e < E_EDGES) atomicAdd(&hist[c.key[y][e] >> 8], 1);
    }
    __syncthreads();
    for (int i = t; i < NBUK; i += 256)
        if (hist[i] > 0) atomicAdd(&c.btot[y * NBUK + i], hist[i]);
}

__global__ void k_bscan(Csr3 c) {
    __shared__ int sh[3 * NBUK];
    int t = threadIdx.x;
    for (int i = t; i < 3 * NBUK; i += 256) sh[i] = c.btot[i];
    __syncthreads();
    if (t < 3) {
        int run = 0;
        int* bs = c.bstart + t * (NBUK + 1);
        for (int b = 0; b < NBUK; b++) {
            bs[b] = run;
            c.bcur[t * NBUK + b] = run;
            run += sh[t * NBUK + b];
        }
        bs[NBUK] = run;
    }
}

__global__ __launch_bounds__(256) void k_bucketA(Csr3 c) {
    __shared__ int hist[NBUK], base[NBUK], off[NBUK];
    const int y = blockIdx.y;
    const int chunk0 = blockIdx.x * 4096;
    const int t = threadIdx.x;
    for (int i = t; i < NBUK; i += 256) { hist[i] = 0; off[i] = 0; }
    __syncthreads();
    int keys[16], vals[16], bks[16];
#pragma unroll
    for (int i = 0; i < 16; i++) {
        int e = chunk0 + (i << 8) + t;
        bool ok = (e < E_EDGES);
        int k = ok ? c.key[y][e] : 0;
        keys[i] = k;
        vals[i] = ok ? ((y == 2) ? e : c.other[y][e]) : 0;
        bks[i] = ok ? (k >> 8) : -1;
        if (ok) atomicAdd(&hist[k >> 8], 1);
    }
    __syncthreads();
    if (t < NBUK && hist[t] > 0) base[t] = atomicAdd(&c.bcur[y * NBUK + t], hist[t]);
    __syncthreads();
    int* ty = c.tmp + (size_t)y * E_EDGES;
#pragma unroll
    for (int i = 0; i < 16; i++) {
        int b = bks[i];
        if (b >= 0) {
            int o = atomicAdd(&off[b], 1);
            ty[base[b] + o] = ((keys[i] & 255) << 24) | vals[i];
        }
    }
}

__global__ __launch_bounds__(256) void k_bucketB(Csr3 c) {
    __shared__ int cnt[256], lbase[256], run[256];
    const int y = blockIdx.y;
    const int b = blockIdx.x;
    const int nbase = b << 8;
    const int t = threadIdx.x;
    cnt[t] = 0; run[t] = 0;
    __syncthreads();
    const int bs = c.bstart[y * (NBUK + 1) + b];
    const int be = c.bstart[y * (NBUK + 1) + b + 1];
    const int* ty = c.tmp + (size_t)y * E_EDGES;
    for (int i = bs + t; i < be; i += 256)
        atomicAdd(&cnt[((unsigned)ty[i]) >> 24], 1);
    __syncthreads();
    int v = cnt[t];
    lbase[t] = v;
    __syncthreads();
    for (int off = 1; off < 256; off <<= 1) {
        int u = (t >= off) ? lbase[t - off] : 0;
        __syncthreads();
        lbase[t] += u;
        __syncthreads();
    }
    int excl = lbase[t] - v;
    __syncthreads();
    lbase[t] = excl;
    __syncthreads();
    int n = nbase + t;
    if (n < N_NODES) c.rowptr[y][n] = bs + excl;
    if (b == NBUK - 1 && t == 0) c.rowptr[y][N_NODES] = E_EDGES;
    int* outy = c.out[y];
    for (int i = bs + t; i < be; i += 256) {
        int u = ty[i];
        int k = ((unsigned)u) >> 24;
        int o = atomicAdd(&run[k], 1);
        outy[bs + lbase[k] + o] = u & 0x00FFFFFF;
    }
}

// ===== merged front kernel: GANConv0 gather | att2 srclist | pool0 =====
// blocks [0,1250): gather_f32; [1250,2500): src_gather; [2500,2813): pool0
struct FrontArgs {
    const float4* x; const int* rowptr0; const int* pay0; unsigned short* z;
    const int* pay2; const int* asrc; int* srclist;
    const int* batch; float* pool0;
};
__global__ __launch_bounds__(256) void k_front(FrontArgs a) {
    const int bx = blockIdx.x, t = threadIdx.x;
    if (bx < 1250) {
        // GANConv0 aggregation: z[n] = bf16(x[n] + sum x[srcs]), unroll-4
        int gid = bx * 256 + t;
        int n = gid >> 4;
        int q = gid & 15;
        float4 acc = a.x[((size_t)n << 4) + q];
        float4 a1 = make_float4(0.f, 0.f, 0.f, 0.f), a2 = a1, a3 = a1;
        int p = a.rowptr0[n], p1 = a.rowptr0[n + 1];
        for (; p + 4 <= p1; p += 4) {
            float4 v0 = a.x[((size_t)a.pay0[p + 0] << 4) + q];
            float4 v1 = a.x[((size_t)a.pay0[p + 1] << 4) + q];
            float4 v2 = a.x[((size_t)a.pay0[p + 2] << 4) + q];
            float4 v3 = a.x[((size_t)a.pay0[p + 3] << 4) + q];
            acc.x += v0.x; acc.y += v0.y; acc.z += v0.z; acc.w += v0.w;
            a1.x += v1.x; a1.y += v1.y; a1.z += v1.z; a1.w += v1.w;
            a2.x += v2.x; a2.y += v2.y; a2.z += v2.z; a2.w += v2.w;
            a3.x += v3.x; a3.y += v3.y; a3.z += v3.z; a3.w += v3.w;
        }
        for (; p < p1; p++) {
            float4 v = a.x[((size_t)a.pay0[p] << 4) + q];
            acc.x += v.x; acc.y += v.y; acc.z += v.z; acc.w += v.w;
        }
        acc.x += a1.x + a2.x + a3.x; acc.y += a1.y + a2.y + a3.y;
        acc.z += a1.z + a2.z + a3.z; acc.w += a1.w + a2.w + a3.w;
        ushort4 o;
        o.x = f2bf(acc.x); o.y = f2bf(acc.y); o.z = f2bf(acc.z); o.w = f2bf(acc.w);
        *(ushort4*)&a.z[((size_t)n << 6) + (q << 2)] = o;
    } else if (bx < 2500) {
        int i = (bx - 1250) * 256 + t;
        a.srclist[i] = a.asrc[a.pay2[i]];
    } else {
        // pool0 over sorted batch (C=64, npb=64)
        int c = t & 63;
        int rofs = t >> 6;
        int i0 = (bx - 2500) * 64;
        int i1 = min(i0 + 64, N_NODES);
        float acc = 0.f;
        int gcur = -1;
        const float* X = (const float*)a.x;
        for (int i = i0 + rofs; i < i1; i += 4) {
            int g = a.batch[i];
            if (g != gcur) {
                if (gcur >= 0) atomicAdd(&a.pool0[gcur * F_INN + c], acc);
                acc = 0.f; gcur = g;
            }
            acc += X[(size_t)i * F_INN + c];
        }
        if (gcur >= 0) atomicAdd(&a.pool0[gcur * F_INN + c], acc);
    }
}

// ===== GANConv1 aggregation with fused BN+relu on load, unroll-4 =====
__global__ __launch_bounds__(256) void k_gather_bn(const u16x8* __restrict__ raw,
                                                   const int* __restrict__ rowptr,
                                                   const int* __restrict__ srcs,
                                                   const float* __restrict__ bn_sums,
                                                   const float* __restrict__ g,
                                                   const float* __restrict__ b,
                                                   u16x8* __restrict__ z) {
    int gid = blockIdx.x * blockDim.x + threadIdx.x;
    int n = gid >> 4;
    if (n >= N_NODES) return;
    int q = gid & 15;
    float sc[8], sh[8];
#pragma unroll
    for (int i = 0; i < 8; i++) {
        int c = (q << 3) + i;
        float mean = bn_sums[c] / N_NODES;
        float istd = rsqrtf(bn_sums[HID + c] / N_NODES - mean * mean + EPSV);
        float s = istd * g[c];
        sc[i] = s;
        sh[i] = b[c] - mean * s;
    }
    u16x8 u0 = raw[((size_t)n << 4) + q];
    float acc[8];
#pragma unroll
    for (int i = 0; i < 8; i++) acc[i] = fmaxf(bf2f(u0[i]) * sc[i] + sh[i], 0.f);
    int p = rowptr[n], p1 = rowptr[n + 1];
    for (; p + 4 <= p1; p += 4) {
        u16x8 v0 = raw[((size_t)srcs[p + 0] << 4) + q];
        u16x8 v1 = raw[((size_t)srcs[p + 1] << 4) + q];
        u16x8 v2 = raw[((size_t)srcs[p + 2] << 4) + q];
        u16x8 v3 = raw[((size_t)srcs[p + 3] << 4) + q];
#pragma unroll
        for (int i = 0; i < 8; i++) {
            acc[i] += fmaxf(bf2f(v0[i]) * sc[i] + sh[i], 0.f)
                    + fmaxf(bf2f(v1[i]) * sc[i] + sh[i], 0.f)
                    + fmaxf(bf2f(v2[i]) * sc[i] + sh[i], 0.f)
                    + fmaxf(bf2f(v3[i]) * sc[i] + sh[i], 0.f);
        }
    }
    for (; p < p1; p++) {
        u16x8 v = raw[((size_t)srcs[p] << 4) + q];
#pragma unroll
        for (int i = 0; i < 8; i++) acc[i] += fmaxf(bf2f(v[i]) * sc[i] + sh[i], 0.f);
    }
    u16x8 o;
#pragma unroll
    for (int i = 0; i < 8; i++) o[i] = f2bf(acc[i]);
    z[((size_t)n << 4) + q] = o;
}

// ===== weight prep: Wt[n][k] = bf16(W[k][n]) for 8 weights in one launch =====
struct WtJob  { const float* src; unsigned short* dst; int K; int N; };
struct WtJobs { WtJob j[8]; };
__global__ void k_wt_cast(WtJobs jobs) {
    WtJob jb = jobs.j[blockIdx.y];
    int total = jb.K * jb.N;
    for (int i = blockIdx.x * blockDim.x + threadIdx.x; i < total; i += gridDim.x * blockDim.x) {
        int nn = i / jb.K, kk = i - nn * jb.K;
        jb.dst[i] = f2bf(jb.src[(size_t)kk * jb.N + nn]);
    }
}

// ===== MFMA bf16 GEMM: C[M,N] = A'[M,K] @ Wt[N,K]^T + bias; bf16 out =====
template <int STATS, int BNA, int TM, int TN, int BIAS2, int SPLIT>
__global__ __launch_bounds__(256) void k_mfma_gemm(const unsigned short* __restrict__ A,
                                                   const unsigned short* __restrict__ Wt,
                                                   const float* __restrict__ biasL,
                                                   const float* __restrict__ biasR,
                                                   unsigned short* __restrict__ Cout,
                                                   int M, int K, int N,
                                                   float* __restrict__ stats_sums,
                                                   const float* __restrict__ bn_sums,
                                                   const float* __restrict__ bn_g,
                                                   const float* __restrict__ bn_b) {
    constexpr int BNF = (TM == 128) ? (TN / 32) : (TN / 64);  // frags per wave (col dir)
    constexpr int BPASS = TN / 64;                            // B-tile load passes
    __shared__ unsigned short As[TM][40];
    __shared__ unsigned short Bs[TN][40];
    __shared__ float s_scale[BNA ? HID : 1], s_shift[BNA ? HID : 1];
    const int t = threadIdx.x;
    if (BNA) {
        if (t < HID) {
            float mean = bn_sums[t] / M;
            float istd = rsqrtf(bn_sums[HID + t] / M - mean * mean + EPSV);
            float s = istd * bn_g[t];
            s_scale[t] = s;
            s_shift[t] = bn_b[t] - mean * s;
        }
        __syncthreads();
    }
    const int wave = t >> 6, lane = t & 63;
    const int row0 = blockIdx.y * TM, col0 = blockIdx.x * TN;
    const int wm = (TM == 128) ? ((wave & 1) << 6) : 0;
    const int wn = (TM == 128) ? ((wave >> 1) << 6)
                               : ((TN == 128) ? (wave << 5) : (wave << 4));
    const int lm = lane & 15, lk = (lane >> 4) << 3;
    constexpr int APASS = TM / 64;
    f32x4 acc[4][BNF] = {};
    for (int k0 = 0; k0 < K; k0 += 32) {
        u16x8 av[APASS], wv[BPASS];
#pragma unroll
        for (int i = 0; i < APASS; i++) {
            int c = t + (i << 8);
            int r = c >> 2, ko = (c & 3) << 3;
            u16x8 zv = {};
            int gr = row0 + r;
            av[i] = (gr < M) ? *(const u16x8*)&A[(size_t)gr * K + k0 + ko] : zv;
            if (BNA) {
#pragma unroll
                for (int j = 0; j < 8; j++) {
                    int kc = k0 + ko + j;
                    float v = fmaxf(bf2f(av[i][j]) * s_scale[kc] + s_shift[kc], 0.f);
                    av[i][j] = f2bf(v);
                }
            }
        }
#pragma unroll
        for (int i = 0; i < BPASS; i++) {
            int c = t + (i << 8);
            int r = c >> 2, ko = (c & 3) << 3;
            wv[i] = *(const u16x8*)&Wt[(size_t)(col0 + r) * K + k0 + ko];
        }
        __syncthreads();
#pragma unroll
        for (int i = 0; i < APASS; i++) {
            int c = t + (i << 8);
            int r = c >> 2, ko = (c & 3) << 3;
            *(u16x8*)&As[r][ko] = av[i];
        }
#pragma unroll
        for (int i = 0; i < BPASS; i++) {
            int c = t + (i << 8);
            int r = c >> 2, ko = (c & 3) << 3;
            *(u16x8*)&Bs[r][ko] = wv[i];
        }
        __syncthreads();
        bf16x8 af[4], bfm[BNF];
#pragma unroll
        for (int i = 0; i < 4; i++) af[i]  = *(const bf16x8*)&As[wm + (i << 4) + lm][lk];
#pragma unroll
        for (int j = 0; j < BNF; j++) bfm[j] = *(const bf16x8*)&Bs[wn + (j << 4) + lm][lk];
#pragma unroll
        for (int i = 0; i < 4; i++)
#pragma unroll
            for (int j = 0; j < BNF; j++)
                acc[i][j] = __builtin_amdgcn_mfma_f32_16x16x32_bf16(af[i], bfm[j], acc[i][j], 0, 0, 0);
    }
    const int lr4 = (lane >> 4) << 2;
    float s1[BNF], s2[BNF];
#pragma unroll
    for (int j = 0; j < BNF; j++) { s1[j] = 0.f; s2[j] = 0.f; }
#pragma unroll
    for (int j = 0; j < BNF; j++) {
        int col = col0 + wn + (j << 4) + lm;
        float bv = BIAS2 ? ((col < 256) ? biasL[col] : biasR[col - 256]) : biasL[col];
        unsigned short* dstp;
        int cl;
        if (SPLIT) {
            if (col < 256) { dstp = Cout; cl = col; }
            else { dstp = Cout + (size_t)N_NODES * 256; cl = col - 256; }
        } else { dstp = Cout; cl = col; }
#pragma unroll
        for (int i = 0; i < 4; i++) {
#pragma unroll
            for (int r = 0; r < 4; r++) {
                int row = row0 + wm + (i << 4) + lr4 + r;
                if (row < M) {
                    float v = acc[i][j][r] + bv;
                    if (SPLIT) dstp[(size_t)row * 256 + cl] = f2bf(v);
                    else       dstp[(size_t)row * N + cl]   = f2bf(v);
                    if (STATS) { s1[j] += v; s2[j] += v * v; }
                }
            }
        }
    }
    if (STATS) {
#pragma unroll
        for (int j = 0; j < BNF; j++) {
            s1[j] += __shfl_xor(s1[j], 16, 64); s1[j] += __shfl_xor(s1[j], 32, 64);
            s2[j] += __shfl_xor(s2[j], 16, 64); s2[j] += __shfl_xor(s2[j], 32, 64);
        }
        if ((lane >> 4) == 0) {
#pragma unroll
            for (int j = 0; j < BNF; j++) {
                int col = col0 + wn + (j << 4) + lm;
                atomicAdd(&stats_sums[col], s1[j]);
                atomicAdd(&stats_sums[HID + col], s2[j]);
            }
        }
    }
}

// ========== fused ATTConv (GATv2): half-wave edge-paired online softmax ==========
// R8 tail fix: 16-wide main loop (8 loads in flight), ONE unmasked 8-edge step,
// then ONE straight-line masked 8-edge group for the <8 remainder. This removes
// the serial pair iterations (R7 goal) without R7's looped dual-path tail that
// bloated VGPR 56->68 and dropped occupancy 31->23%.
#define ATT_CAP 192
#define LOG2E   1.4426950408889634f
#define DTHR    11.0f

__device__ __forceinline__ float att_logit8(u16x8 uv, const float* xr8, const float* at8, float* x8) {
    float tl = 0.f;
#pragma unroll
    for (int i = 0; i < 8; i++) {
        x8[i] = bf2f(uv[i]);
        float v = x8[i] + xr8[i];
        v = fmaxf(v, 0.2f * v);     // leaky_relu(v,0.2): max(v,0.2v) exact for all v
        tl = fmaf(at8[i], v, tl);
    }
    return tl;
}

template <int CTRL>
__device__ __forceinline__ float dpp_add(float x) {
    int y = __builtin_amdgcn_update_dpp(0, __float_as_int(x), CTRL, 0xF, 0xF, true);
    return x + __int_as_float(y);
}

// sum across each 16-lane group, all lanes get result; pure VALU (no LDS)
__device__ __forceinline__ float red16(float tl) {
    tl = dpp_add<0xB1>(tl);    // quad_perm [1,0,3,2]  (xor 1)
    tl = dpp_add<0x4E>(tl);    // quad_perm [2,3,0,1]  (xor 2)
    tl = dpp_add<0x124>(tl);   // row_ror:4 (quad-sum rotate)
    tl = dpp_add<0x128>(tl);   // row_ror:8
    return tl;
}

// one 8-edge group (4 edges per half-wave); MASKED adds per-edge validity vm[]
template <int WITH_ALPHA, int MASKED>
__device__ __forceinline__ void att_group4(const u16x8* uv, const float* vm, int ebase, int p0,
                                           int half, int j, int h,
                                           const float* xr8, const float* at8,
                                           float& m, float& ssum, float* acc,
                                           float (*slg)[2]) {
    float x8[4][8], tl[4];
#pragma unroll
    for (int g = 0; g < 4; g++) tl[g] = att_logit8(uv[g], xr8, at8, x8[g]);
#pragma unroll
    for (int g = 0; g < 4; g++) tl[g] = red16(tl[g]);
    if (MASKED) {
#pragma unroll
        for (int g = 0; g < 4; g++) tl[g] = (vm[g] != 0.f) ? tl[g] : -1e30f;
    }
    if (WITH_ALPHA && (j & 15) == 0) {
#pragma unroll
        for (int g = 0; g < 4; g++) {
            int idx = ebase + (g << 1) + half - p0;
            bool ok = MASKED ? (vm[g] != 0.f) : true;
            if (ok && idx < ATT_CAP) slg[idx][h] = tl[g];
        }
    }
    float pm = fmaxf(fmaxf(tl[0], tl[1]), fmaxf(tl[2], tl[3]));
    if (__builtin_expect(!__all(pm <= m + DTHR), 0)) {
        // rare rescale path: full sequential online update
#pragma unroll
        for (int g = 0; g < 4; g++) {
            float mn = fmaxf(m, tl[g]);
            float sc = fexp2(m - mn);
            float w  = fexp2(tl[g] - mn);
            if (MASKED) w *= vm[g];
            ssum = ssum * sc + w;
#pragma unroll
            for (int i = 0; i < 8; i++) acc[i] = acc[i] * sc + w * x8[g][i];
            m = mn;
        }
    } else {
        float w0 = fexp2(tl[0] - m), w1 = fexp2(tl[1] - m);
        float w2 = fexp2(tl[2] - m), w3 = fexp2(tl[3] - m);
        if (MASKED) { w0 *= vm[0]; w1 *= vm[1]; w2 *= vm[2]; w3 *= vm[3]; }
        ssum += (w0 + w1) + (w2 + w3);
#pragma unroll
        for (int i = 0; i < 8; i++)
            acc[i] += (w0 * x8[0][i] + w1 * x8[1][i]) + (w2 * x8[2][i] + w3 * x8[3][i]);
    }
}

template <int CONCAT, int WITH_ALPHA>
__global__ __launch_bounds__(256) void k_att_fused(const u16x8* __restrict__ XL,
                                                   const u16x8* __restrict__ XR,
                                                   const int* __restrict__ rowptr,
                                                   const int* __restrict__ plist,
                                                   const int* __restrict__ srclist,
                                                   const float* __restrict__ att,
                                                   const float* __restrict__ bias,
                                                   void* __restrict__ outp,
                                                   float* __restrict__ alpha_out) {
    __shared__ float s_lg[WITH_ALPHA ? 4 : 1][WITH_ALPHA ? ATT_CAP : 1][2];
    const int t = threadIdx.x;
    const int wave = t >> 6, l = t & 63;
    const int n = blockIdx.x * 4 + wave;   // N_NODES % 4 == 0
    const int half = l >> 5;               // which edge of the pair this lane serves
    const int j = l & 31;                  // channel group: channels 8j..8j+7
    const int h = j >> 4;                  // head

    // xr slice (8 channels) + att row (pre-scaled by log2e -> logits in log2 domain)
    u16x8 ur = XR[((size_t)n << 5) + j];
    float xr8[8];
#pragma unroll
    for (int i = 0; i < 8; i++) xr8[i] = bf2f(ur[i]);
    const float* ap = &att[h * HID + ((j & 15) << 3)];
    float at8[8];
#pragma unroll
    for (int i = 0; i < 8; i++) at8[i] = ap[i] * LOG2E;

    const int p0 = rowptr[n], p1 = rowptr[n + 1];
    const int* PL = WITH_ALPHA ? srclist : plist;
    const int deg = p1 - p0;
    // idx preload: lane l holds src of edge l (first 64 edges), fetched via bpermute
    int idxreg = (deg > 0) ? PL[p0 + ((l < deg) ? l : (deg - 1))] : 0;

    float m = -1e30f, ssum = 0.f;      // finite sentinel: avoids inf-inf NaNs
    float acc[8] = {};
    float (*slg)[2] = WITH_ALPHA ? s_lg[wave] : nullptr;

    int p = p0;
    // ---- wide main loop: 16 edges (8 row loads in flight) per iteration ----
    for (; p + 16 <= p1; p += 16) {
        int rb = p - p0;
        int sA[4], sB[4];
        if (rb + 16 <= 64) {
#pragma unroll
            for (int g = 0; g < 4; g++)
                sA[g] = __builtin_amdgcn_ds_bpermute((rb + (g << 1) + half) << 2, idxreg);
#pragma unroll
            for (int g = 0; g < 4; g++)
                sB[g] = __builtin_amdgcn_ds_bpermute((rb + 8 + (g << 1) + half) << 2, idxreg);
        } else {
#pragma unroll
            for (int g = 0; g < 4; g++) sA[g] = PL[p + (g << 1) + half];
#pragma unroll
            for (int g = 0; g < 4; g++) sB[g] = PL[p + 8 + (g << 1) + half];
        }
        u16x8 uvA[4], uvB[4];
#pragma unroll
        for (int g = 0; g < 4; g++) uvA[g] = XL[((size_t)sA[g] << 5) + j];
#pragma unroll
        for (int g = 0; g < 4; g++) uvB[g] = XL[((size_t)sB[g] << 5) + j];
        att_group4<WITH_ALPHA, 0>(uvA, nullptr, p,     p0, half, j, h, xr8, at8, m, ssum, acc, slg);
        att_group4<WITH_ALPHA, 0>(uvB, nullptr, p + 8, p0, half, j, h, xr8, at8, m, ssum, acc, slg);
    }
    // ---- one unmasked 8-edge step (remainder >= 8) ----
    if (p + 8 <= p1) {
        int rb = p - p0;
        int s4[4];
        if (rb + 8 <= 64) {
#pragma unroll
            for (int g = 0; g < 4; g++)
                s4[g] = __builtin_amdgcn_ds_bpermute((rb + (g << 1) + half) << 2, idxreg);
        } else {
#pragma unroll
            for (int g = 0; g < 4; g++) s4[g] = PL[p + (g << 1) + half];
        }
        u16x8 uv[4];
#pragma unroll
        for (int g = 0; g < 4; g++) uv[g] = XL[((size_t)s4[g] << 5) + j];
        att_group4<WITH_ALPHA, 0>(uv, nullptr, p, p0, half, j, h, xr8, at8, m, ssum, acc, slg);
        p += 8;
    }
    // ---- one straight-line masked group covers the final <8 edges ----
    if (p < p1) {
        int rb = p - p0;
        int s4[4];
        float vm[4];
        const bool inwin = (rb + 8 <= 64);
#pragma unroll
        for (int g = 0; g < 4; g++) {
            int li = rb + (g << 1) + half;          // edge index within row
            bool ok = li < deg;
            vm[g] = ok ? 1.f : 0.f;
            int lic = ok ? li : (deg - 1);
            if (inwin) s4[g] = __builtin_amdgcn_ds_bpermute(lic << 2, idxreg);
            else       s4[g] = PL[p0 + lic];
        }
        u16x8 uv[4];
#pragma unroll
        for (int g = 0; g < 4; g++) uv[g] = XL[((size_t)s4[g] << 5) + j];
        att_group4<WITH_ALPHA, 1>(uv, vm, p, p0, half, j, h, xr8, at8, m, ssum, acc, slg);
    }

    // ---- merge the two half-wave softmax states (symmetric: both halves get result) ----
    float m_o = __shfl_xor(m, 32, 64);
    float mf  = fmaxf(m, m_o);
    float sA  = fexp2(m - mf);             // m,mf finite -> 0-edge case gives sA=1
    float ssA = ssum * sA;
    float ssum_f = ssA + __shfl_xor(ssA, 32, 64);
    float accf[8];
#pragma unroll
    for (int i = 0; i < 8; i++) {
        float a = acc[i] * sA;
        accf[i] = a + __shfl_xor(a, 32, 64);
    }
    float inv = 1.f / (ssum_f + 1e-16f);

    // ---- alpha output (att2): parallel from LDS cache ----
    if (WITH_ALPHA) {
        float m_oh   = __shfl_xor(mf, 16, 64);
        float inv_oh = __shfl_xor(inv, 16, 64);
        float m2[2], i2[2];
        m2[h] = mf;  m2[1 - h] = m_oh;
        i2[h] = inv; i2[1 - h] = inv_oh;
        int cnt = p1 - p0;
        int ccnt = (cnt < ATT_CAP) ? cnt : ATT_CAP;
        for (int i = l; i < ccnt * 2; i += 64) {
            int idx = i >> 1, hh = i & 1;
            float a = fexp2(s_lg[wave][idx][hh] - m2[hh]) * i2[hh];
            alpha_out[plist[p0 + idx] * HEADS + hh] = a;
        }
        // overflow fallback (deg > ATT_CAP): serial recompute (practically never taken)
        for (int pp = p0 + ATT_CAP; pp < p1; pp++) {
            int src = PL[pp];
            u16x8 uv = XL[((size_t)src << 5) + j];
            float x8[8], tl;
            tl = att_logit8(uv, xr8, at8, x8);
            tl = red16(tl);
            if ((j & 15) == 0 && half == 0)
                alpha_out[plist[pp] * HEADS + h] = fexp2(tl - mf) * inv;
        }
    }

    // ---- epilogue ----
    if (CONCAT) {
        if (half == 0) {
            const float* bp = &bias[j << 3];
            u16x8 o;
#pragma unroll
            for (int i = 0; i < 8; i++) o[i] = f2bf(fmaxf(accf[i] * inv + bp[i], 0.f));
            ((u16x8*)outp)[((size_t)n << 5) + j] = o;
        }
    } else {
        float om[8];
#pragma unroll
        for (int i = 0; i < 8; i++) {
            float v = accf[i] * inv;
            om[i] = 0.5f * (v + __shfl_xor(v, 16, 64));
        }
        if (half == 0 && h == 0) {
            const float* bp = &bias[j << 3];
            float4 o0, o1;
            o0.x = fmaxf(om[0] + bp[0], 0.f); o0.y = fmaxf(om[1] + bp[1], 0.f);
            o0.z = fmaxf(om[2] + bp[2], 0.f); o0.w = fmaxf(om[3] + bp[3], 0.f);
            o1.x = fmaxf(om[4] + bp[4], 0.f); o1.y = fmaxf(om[5] + bp[5], 0.f);
            o1.z = fmaxf(om[6] + bp[6], 0.f); o1.w = fmaxf(om[7] + bp[7], 0.f);
            ((float4*)outp)[((size_t)n << 5) + (j << 1)]     = o0;
            ((float4*)outp)[((size_t)n << 5) + (j << 1) + 1] = o1;
        }
    }
}

// ================= pooling over sorted batch_index (node-parallel) =================
template <int C>
__global__ __launch_bounds__(256) void k_pool_atomic(const float* __restrict__ X,
                                                     const int* __restrict__ batch,
                                                     float* __restrict__ pool, int npb) {
    const int RP = 256 / C;
    int c = threadIdx.x & (C - 1);
    int rofs = threadIdx.x / C;
    int i0 = blockIdx.x * npb;
    int i1 = min(i0 + npb, N_NODES);
    float acc = 0.f;
    int gcur = -1;
    for (int i = i0 + rofs; i < i1; i += RP) {
        int g = batch[i];
        if (g != gcur) {
            if (gcur >= 0) atomicAdd(&pool[gcur * C + c], acc);
            acc = 0.f; gcur = g;
        }
        acc += X[(size_t)i * C + c];
    }
    if (gcur >= 0) atomicAdd(&pool[gcur * C + c], acc);
}

// ================= final prediction head =================
__global__ void k_head(const float* __restrict__ pool0, const float* __restrict__ poolL,
                       const float* __restrict__ p0w, const float* __restrict__ p0b,
                       const float* __restrict__ pLw, const float* __restrict__ pLb,
                       const float* __restrict__ ow, const float* __restrict__ ob,
                       float* __restrict__ outputs) {
    int g = blockIdx.x;
    int m = threadIdx.x;
    __shared__ float sh[MIDD];
    if (m < MIDD) {
        float s = p0b[m] + pLb[m];
        for (int k = 0; k < F_INN; k++) s += pool0[g * F_INN + k] * p0w[k * MIDD + m];
        for (int k = 0; k < HID; k++)  s += poolL[g * HID + k] * pLw[k * MIDD + m];
        sh[m] = fmaxf(s, 0.f);
    }
    __syncthreads();
    if (m == 0) {
        float s = ob[0];
        for (int k = 0; k < MIDD; k++) s += sh[k] * ow[k];
        outputs[g] = s;
    }
}

extern "C" void kernel_launch(void* const* d_in, const int* in_sizes, int n_in,
                              void* d_out, int out_size, void* d_ws, size_t ws_size,
                              hipStream_t stream) {
    // ---- inputs ----
    const float* x      = (const float*)d_in[0];
    const int*   ei     = (const int*)d_in[1];
    const int*   aei    = (const int*)d_in[2];
    const int*   batch  = (const int*)d_in[3];
    const float* g0_w1  = (const float*)d_in[4];
    const float* g0_b1  = (const float*)d_in[5];
    const float* g0_bng = (const float*)d_in[6];
    const float* g0_bnb = (const float*)d_in[7];
    const float* g0_w2  = (const float*)d_in[8];
    const float* g0_b2  = (const float*)d_in[9];
    const float* g1_w1  = (const float*)d_in[10];
    const float* g1_b1  = (const float*)d_in[11];
    const float* g1_bng = (const float*)d_in[12];
    const float* g1_bnb = (const float*)d_in[13];
    const float* g1_w2  = (const float*)d_in[14];
    const float* g1_b2  = (const float*)d_in[15];
    const float* bn0_g  = (const float*)d_in[16];
    const float* bn0_b  = (const float*)d_in[17];
    const float* bn1_g  = (const float*)d_in[18];
    const float* bn1_b  = (const float*)d_in[19];
    const float* a1_wl  = (const float*)d_in[20];
    const float* a1_bl  = (const float*)d_in[21];
    const float* a1_wr  = (const float*)d_in[22];
    const float* a1_br  = (const float*)d_in[23];
    const float* a1_att = (const float*)d_in[24];
    const float* a1_bias= (const float*)d_in[25];
    const float* a2_wl  = (const float*)d_in[26];
    const float* a2_bl  = (const float*)d_in[27];
    const float* a2_wr  = (const float*)d_in[28];
    const float* a2_br  = (const float*)d_in[29];
    const float* a2_att = (const float*)d_in[30];
    const float* a2_bias= (const float*)d_in[31];
    const float* p0w    = (const float*)d_in[32];
    const float* p0b    = (const float*)d_in[33];
    const float* pLw    = (const float*)d_in[34];
    const float* pLb    = (const float*)d_in[35];
    const float* ow     = (const float*)d_in[36];
    const float* ob     = (const float*)d_in[37];

    // ---- outputs ----
    float* out_head  = (float*)d_out;
    float* atten_out = out_head + G_GR;
    float* alpha_out = atten_out + (size_t)N_NODES * HID;

    // ---- workspace ----
    float* ws = (float*)d_ws;
    float* sums4 = ws;                                 // 4*256 (s0|s1|s2|s3)
    float* pool0 = sums4 + 4 * 256;                    // G*64
    float* poolL = pool0 + G_GR * F_INN;               // G*128
    int*   btot  = (int*)(poolL + G_GR * HID);         // 3*NBUK (zeroed)
    const size_t zero_bytes = (4 * 256 + G_GR * F_INN + G_GR * HID + 3 * NBUK) * 4;

    int* ip = btot + 3 * NBUK;
    int* bstart = ip; ip += 3 * (NBUK + 1);
    int* bcur   = ip; ip += 3 * NBUK;
    int* rowptr[3]; int* payload[3];
    for (int c = 0; c < 3; c++) {
        rowptr[c]  = ip; ip += N_NODES + 1;
        payload[c] = ip; ip += E_EDGES;
    }
    int* tmp3 = ip; ip += 3 * E_EDGES;                 // [3][E] packed int
    int* srclist = tmp3;                               // reuse: tmp3 dead after bucketB
    const size_t NB = (size_t)N_NODES * HC;
    unsigned short* B1 = (unsigned short*)ip;          // [N,HC] bf16
    unsigned short* B2 = B1 + NB;                      // [N,HC] bf16
    unsigned short* Qb = B2 + NB;                      // XL [N,256] | XR [N,256] bf16
    unsigned short* g0w1t = Qb + 2 * NB;
    unsigned short* g0w2t = g0w1t + 128 * 64;
    unsigned short* g1w1t = g0w2t + 128 * 128;
    unsigned short* g1w2t = g1w1t + 128 * 128;
    unsigned short* a1wlt = g1w2t + 128 * 128;         // [256,128]
    unsigned short* a1wrt = a1wlt + 256 * 128;         // contiguous -> [512,128]
    unsigned short* a2wlt = a1wrt + 256 * 128;         // [256,256]
    unsigned short* a2wrt = a2wlt + 256 * 256;         // contiguous -> [512,256]

    unsigned short* XLb = Qb;                          // xl rows (gathered per edge)
    unsigned short* XRb = Qb + (size_t)N_NODES * 256;  // xr rows (read once per node)

    const int* e_row = ei;
    const int* e_col = ei + E_EDGES;
    const int* a_src = aei;
    const int* a_dst = aei + E_EDGES;

    const int TB = 256;
#define GRID1(n) dim3(CDIV((n), TB))

    // ===== weight transpose+cast =====
    {
        WtJobs jobs;
        jobs.j[0] = {g0_w1, g0w1t, F_INN, HID};
        jobs.j[1] = {g0_w2, g0w2t, HID,   HID};
        jobs.j[2] = {g1_w1, g1w1t, HID,   HID};
        jobs.j[3] = {g1_w2, g1w2t, HID,   HID};
        jobs.j[4] = {a1_wl, a1wlt, HID,   HC};
        jobs.j[5] = {a1_wr, a1wrt, HID,   HC};
        jobs.j[6] = {a2_wl, a2wlt, HC,    HC};
        jobs.j[7] = {a2_wr, a2wrt, HC,    HC};
        k_wt_cast<<<dim3(32, 8), TB, 0, stream>>>(jobs);
    }

    // ===== zero sums/pools/btot in one shot; build 3 CSRs (bucket-granular) =====
    (void)hipMemsetAsync(sums4, 0, zero_bytes, stream);
    {
        Csr3 c;
        c.key[0] = e_row; c.other[0] = e_col;
        c.key[1] = e_col; c.other[1] = e_row;
        c.key[2] = a_dst; c.other[2] = a_src;
        c.btot = btot; c.bstart = bstart; c.bcur = bcur; c.tmp = tmp3;
        for (int i = 0; i < 3; i++) { c.rowptr[i] = rowptr[i]; c.out[i] = payload[i]; }
        k_bhist<<<dim3(CDIV(E_EDGES, 4096), 3), TB, 0, stream>>>(c);
        k_bscan<<<dim3(1), TB, 0, stream>>>(c);
        k_bucketA<<<dim3(CDIV(E_EDGES, 4096), 3), TB, 0, stream>>>(c);
        k_bucketB<<<dim3(NBUK, 3), TB, 0, stream>>>(c);
    }

    // ===== merged front: GANConv0 gather | att2 srclist | pool0 (one dispatch) =====
    {
        FrontArgs fa;
        fa.x = (const float4*)x; fa.rowptr0 = rowptr[0]; fa.pay0 = payload[0];
        fa.z = B1;
        fa.pay2 = payload[2]; fa.asrc = a_src; fa.srclist = srclist;
        fa.batch = batch; fa.pool0 = pool0;
        k_front<<<dim3(2813), TB, 0, stream>>>(fa);
    }

    const dim3 gemm_g1(2, CDIV(N_NODES, 64));    // N=128 as 2x64-col tiles (626 blocks)
    const dim3 gemm_gq(4, CDIV(N_NODES, 128));   // N=512, TM=128 (628 blocks)
    const float* NOF = nullptr;

    // ===== GANConv 0 (ping-pong B1/B2 as [N,128]) =====
    k_mfma_gemm<1, 0, 64, 64, 0, 0><<<gemm_g1, TB, 0, stream>>>(B1, g0w1t, g0_b1, NOF, B2, N_NODES, F_INN, HID,
                                                                sums4 + 0, NOF, NOF, NOF);
    k_mfma_gemm<1, 1, 64, 64, 0, 0><<<gemm_g1, TB, 0, stream>>>(B2, g0w2t, g0_b2, NOF, B1, N_NODES, HID, HID,
                                                                sums4 + 256, sums4 + 0, g0_bng, g0_bnb);
    // raw2 (pre-bn0) in B1

    // ===== GANConv 1 =====
    k_gather_bn<<<GRID1(N_NODES * 16), TB, 0, stream>>>((const u16x8*)B1, rowptr[0], payload[0],
                                                        sums4 + 256, bn0_g, bn0_b, (u16x8*)B2);
    k_mfma_gemm<1, 0, 64, 64, 0, 0><<<gemm_g1, TB, 0, stream>>>(B2, g1w1t, g1_b1, NOF, B1, N_NODES, HID, HID,
                                                                sums4 + 512, NOF, NOF, NOF);
    k_mfma_gemm<1, 1, 64, 64, 0, 0><<<gemm_g1, TB, 0, stream>>>(B1, g1w2t, g1_b2, NOF, B2, N_NODES, HID, HID,
                                                                sums4 + 768, sums4 + 512, g1_bng, g1_bnb);
    // raw4 (pre-bn1 = h2 raw) in B2

    // ===== ATTConv 1 (dst=e_col, concat=True): merged wl|wr GEMM -> XL|XR =====
    k_mfma_gemm<0, 1, 128, 128, 1, 1><<<gemm_gq, TB, 0, stream>>>(B2, a1wlt, a1_bl, a1_br, XLb, N_NODES, HID, 512,
                                                                  nullptr, sums4 + 768, bn1_g, bn1_b);
    k_att_fused<1, 0><<<dim3(N_NODES / 4), TB, 0, stream>>>(
        (const u16x8*)XLb, (const u16x8*)XRb, rowptr[1], payload[1], nullptr,
        a1_att, a1_bias, (void*)B1, nullptr);
    // emb bf16 in B1 [N,HC]

    // ===== ATTConv 2 (dst=a_dst, concat=False): merged GEMM K=256 -> XL|XR =====
    k_mfma_gemm<0, 0, 128, 128, 1, 1><<<gemm_gq, TB, 0, stream>>>(B1, a2wlt, a2_bl, a2_br, XLb, N_NODES, HC, 512,
                                                                  nullptr, NOF, NOF, NOF);
    k_att_fused<0, 1><<<dim3(N_NODES / 4), TB, 0, stream>>>(
        (const u16x8*)XLb, (const u16x8*)XRb, rowptr[2], payload[2], srclist,
        a2_att, a2_bias, (void*)atten_out, alpha_out);

    // ===== pooling + head =====
    k_pool_atomic<HID><<<dim3(CDIV(N_NODES, 64)), TB, 0, stream>>>(atten_out, batch, poolL, 64);
    k_head<<<dim3(G_GR), 64, 0, stream>>>(pool0, poolL, p0w, p0b, pLw, pLb, ow, ob, out_head);
}

// Round 9
// 415.317 us; speedup vs baseline: 1.0155x; 1.0155x over previous
//
#include <hip/hip_runtime.h>
#include <hip/hip_bf16.h>

#define N_NODES 20000
#define E_EDGES 320000
#define F_INN   64
#define HID     128
#define HEADS   2
#define HC      (HEADS * HID)   // 256
#define G_GR    64
#define MIDD    32
#define EPSV    1e-5f
#define NBUK    79              // ceil(20000/256); bucket = node >> 8

#define CDIV(a, b) (((a) + (b) - 1) / (b))

typedef __attribute__((ext_vector_type(8))) short          bf16x8;  // MFMA A/B frag
typedef __attribute__((ext_vector_type(4))) float          f32x4;   // MFMA C/D frag
typedef __attribute__((ext_vector_type(8))) unsigned short u16x8;

// ---------- bf16 helpers (RNE) ----------
__device__ inline float bf2f(unsigned short u) { return __uint_as_float((unsigned)u << 16); }
__device__ inline unsigned short f2bf(float f) {
    unsigned u = __float_as_uint(f);
    unsigned r = u + 0x7FFFu + ((u >> 16) & 1u);
    return (unsigned short)(r >> 16);
}

#if __has_builtin(__builtin_amdgcn_exp2f)
__device__ inline float fexp2(float x) { return __builtin_amdgcn_exp2f(x); }
#else
__device__ inline float fexp2(float x) { return exp2f(x); }
#endif

// ================= CSR construction (3 CSRs, bucket-granular two-pass) ========
// tmp entry packed: (key & 255) << 24 | payload   (payload < 2^24: edge id < 320k)
struct Csr3 {
    const int* key[3];
    const int* other[3];   // payload source for y=0,1; y=2 stores edge id
    int* btot;      // [3*NBUK] bucket totals (zeroed)
    int* bstart;    // [3*(NBUK+1)] bucket starts
    int* bcur;      // [3*NBUK] bucket cursors
    int* rowptr[3]; // [N+1] (written by bucketB)
    int* out[3];    // [E] payload (final, CSR order)
    int* tmp;       // [3*E] packed (key_local,payload) bucket-partitioned
};

__global__ __launch_bounds__(256) void k_bhist(Csr3 c) {
    __shared__ int hist[NBUK];
    const int y = blockIdx.y;
    const int chunk0 = blockIdx.x * 4096;
    const int t = threadIdx.x;
    for (int i = t; i < NBUK; i += 256) hist[i] = 0;
    __syncthreads();
#pragma unroll
    for (int i = 0; i < 16; i++) {
        int e = chunk0 + (i << 8) + t;
        if (e < E_EDGES) atomicAdd(&hist[c.key[y][e] >> 8], 1);
    }
    __syncthreads();
    for (int i = t; i < NBUK; i += 256)
        if (hist[i] > 0) atomicAdd(&c.btot[y * NBUK + i], hist[i]);
}

__global__ void k_bscan(Csr3 c) {
    __shared__ int sh[3 * NBUK];
    int t = threadIdx.x;
    for (int i = t; i < 3 * NBUK; i += 256) sh[i] = c.btot[i];
    __syncthreads();
    if (t < 3) {
        int run = 0;
        int* bs = c.bstart + t * (NBUK + 1);
        for (int b = 0; b < NBUK; b++) {
            bs[b] = run;
            c.bcur[t * NBUK + b] = run;
            run += sh[t * NBUK + b];
        }
        bs[NBUK] = run;
    }
}

__global__ __launch_bounds__(256) void k_bucketA(Csr3 c) {
    __shared__ int hist[NBUK], base[NBUK], off[NBUK];
    const int y = blockIdx.y;
    const int chunk0 = blockIdx.x * 4096;
    const int t = threadIdx.x;
    for (int i = t; i < NBUK; i += 256) { hist[i] = 0; off[i] = 0; }
    __syncthreads();
    int keys[16], vals[16], bks[16];
#pragma unroll
    for (int i = 0; i < 16; i++) {
        int e = chunk0 + (i << 8) + t;
        bool ok = (e < E_EDGES);
        int k = ok ? c.key[y][e] : 0;
        keys[i] = k;
        vals[i] = ok ? ((y == 2) ? e : c.other[y][e]) : 0;
        bks[i] = ok ? (k >> 8) : -1;
        if (ok) atomicAdd(&hist[k >> 8], 1);
    }
    __syncthreads();
    if (t < NBUK && hist[t] > 0) base[t] = atomicAdd(&c.bcur[y * NBUK + t], hist[t]);
    __syncthreads();
    int* ty = c.tmp + (size_t)y * E_EDGES;
#pragma unroll
    for (int i = 0; i < 16; i++) {
        int b = bks[i];
        if (b >= 0) {
            int o = atomicAdd(&off[b], 1);
            ty[base[b] + o] = ((keys[i] & 255) << 24) | vals[i];
        }
    }
}

__global__ __launch_bounds__(256) void k_bucketB(Csr3 c) {
    __shared__ int cnt[256], lbase[256], run[256];
    const int y = blockIdx.y;
    const int b = blockIdx.x;
    const int nbase = b << 8;
    const int t = threadIdx.x;
    cnt[t] = 0; run[t] = 0;
    __syncthreads();
    const int bs = c.bstart[y * (NBUK + 1) + b];
    const int be = c.bstart[y * (NBUK + 1) + b + 1];
    const int* ty = c.tmp + (size_t)y * E_EDGES;
    for (int i = bs + t; i < be; i += 256)
        atomicAdd(&cnt[((unsigned)ty[i]) >> 24], 1);
    __syncthreads();
    int v = cnt[t];
    lbase[t] = v;
    __syncthreads();
    for (int off = 1; off < 256; off <<= 1) {
        int u = (t >= off) ? lbase[t - off] : 0;
        __syncthreads();
        lbase[t] += u;
        __syncthreads();
    }
    int excl = lbase[t] - v;
    __syncthreads();
    lbase[t] = excl;
    __syncthreads();
    int n = nbase + t;
    if (n < N_NODES) c.rowptr[y][n] = bs + excl;
    if (b == NBUK - 1 && t == 0) c.rowptr[y][N_NODES] = E_EDGES;
    int* outy = c.out[y];
    for (int i = bs + t; i < be; i += 256) {
        int u = ty[i];
        int k = ((unsigned)u) >> 24;
        int o = atomicAdd(&run[k], 1);
        outy[bs + lbase[k] + o] = u & 0x00FFFFFF;
    }
}

// ===== merged front kernel: GANConv0 gather | att2 srclist | pool0 =====
// blocks [0,1250): gather_f32; [1250,2500): src_gather; [2500,2813): pool0
struct FrontArgs {
    const float4* x; const int* rowptr0; const int* pay0; unsigned short* z;
    const int* pay2; const int* asrc; int* srclist;
    const int* batch; float* pool0;
};
__global__ __launch_bounds__(256) void k_front(FrontArgs a) {
    const int bx = blockIdx.x, t = threadIdx.x;
    if (bx < 1250) {
        // GANConv0 aggregation: z[n] = bf16(x[n] + sum x[srcs]), unroll-4
        int gid = bx * 256 + t;
        int n = gid >> 4;
        int q = gid & 15;
        float4 acc = a.x[((size_t)n << 4) + q];
        float4 a1 = make_float4(0.f, 0.f, 0.f, 0.f), a2 = a1, a3 = a1;
        int p = a.rowptr0[n], p1 = a.rowptr0[n + 1];
        for (; p + 4 <= p1; p += 4) {
            float4 v0 = a.x[((size_t)a.pay0[p + 0] << 4) + q];
            float4 v1 = a.x[((size_t)a.pay0[p + 1] << 4) + q];
            float4 v2 = a.x[((size_t)a.pay0[p + 2] << 4) + q];
            float4 v3 = a.x[((size_t)a.pay0[p + 3] << 4) + q];
            acc.x += v0.x; acc.y += v0.y; acc.z += v0.z; acc.w += v0.w;
            a1.x += v1.x; a1.y += v1.y; a1.z += v1.z; a1.w += v1.w;
            a2.x += v2.x; a2.y += v2.y; a2.z += v2.z; a2.w += v2.w;
            a3.x += v3.x; a3.y += v3.y; a3.z += v3.z; a3.w += v3.w;
        }
        for (; p < p1; p++) {
            float4 v = a.x[((size_t)a.pay0[p] << 4) + q];
            acc.x += v.x; acc.y += v.y; acc.z += v.z; acc.w += v.w;
        }
        acc.x += a1.x + a2.x + a3.x; acc.y += a1.y + a2.y + a3.y;
        acc.z += a1.z + a2.z + a3.z; acc.w += a1.w + a2.w + a3.w;
        ushort4 o;
        o.x = f2bf(acc.x); o.y = f2bf(acc.y); o.z = f2bf(acc.z); o.w = f2bf(acc.w);
        *(ushort4*)&a.z[((size_t)n << 6) + (q << 2)] = o;
    } else if (bx < 2500) {
        int i = (bx - 1250) * 256 + t;
        a.srclist[i] = a.asrc[a.pay2[i]];
    } else {
        // pool0 over sorted batch (C=64, npb=64)
        int c = t & 63;
        int rofs = t >> 6;
        int i0 = (bx - 2500) * 64;
        int i1 = min(i0 + 64, N_NODES);
        float acc = 0.f;
        int gcur = -1;
        const float* X = (const float*)a.x;
        for (int i = i0 + rofs; i < i1; i += 4) {
            int g = a.batch[i];
            if (g != gcur) {
                if (gcur >= 0) atomicAdd(&a.pool0[gcur * F_INN + c], acc);
                acc = 0.f; gcur = g;
            }
            acc += X[(size_t)i * F_INN + c];
        }
        if (gcur >= 0) atomicAdd(&a.pool0[gcur * F_INN + c], acc);
    }
}

// ===== GANConv1 aggregation with fused BN+relu on load, unroll-4 =====
__global__ __launch_bounds__(256) void k_gather_bn(const u16x8* __restrict__ raw,
                                                   const int* __restrict__ rowptr,
                                                   const int* __restrict__ srcs,
                                                   const float* __restrict__ bn_sums,
                                                   const float* __restrict__ g,
                                                   const float* __restrict__ b,
                                                   u16x8* __restrict__ z) {
    int gid = blockIdx.x * blockDim.x + threadIdx.x;
    int n = gid >> 4;
    if (n >= N_NODES) return;
    int q = gid & 15;
    float sc[8], sh[8];
#pragma unroll
    for (int i = 0; i < 8; i++) {
        int c = (q << 3) + i;
        float mean = bn_sums[c] / N_NODES;
        float istd = rsqrtf(bn_sums[HID + c] / N_NODES - mean * mean + EPSV);
        float s = istd * g[c];
        sc[i] = s;
        sh[i] = b[c] - mean * s;
    }
    u16x8 u0 = raw[((size_t)n << 4) + q];
    float acc[8];
#pragma unroll
    for (int i = 0; i < 8; i++) acc[i] = fmaxf(bf2f(u0[i]) * sc[i] + sh[i], 0.f);
    int p = rowptr[n], p1 = rowptr[n + 1];
    for (; p + 4 <= p1; p += 4) {
        u16x8 v0 = raw[((size_t)srcs[p + 0] << 4) + q];
        u16x8 v1 = raw[((size_t)srcs[p + 1] << 4) + q];
        u16x8 v2 = raw[((size_t)srcs[p + 2] << 4) + q];
        u16x8 v3 = raw[((size_t)srcs[p + 3] << 4) + q];
#pragma unroll
        for (int i = 0; i < 8; i++) {
            acc[i] += fmaxf(bf2f(v0[i]) * sc[i] + sh[i], 0.f)
                    + fmaxf(bf2f(v1[i]) * sc[i] + sh[i], 0.f)
                    + fmaxf(bf2f(v2[i]) * sc[i] + sh[i], 0.f)
                    + fmaxf(bf2f(v3[i]) * sc[i] + sh[i], 0.f);
        }
    }
    for (; p < p1; p++) {
        u16x8 v = raw[((size_t)srcs[p] << 4) + q];
#pragma unroll
        for (int i = 0; i < 8; i++) acc[i] += fmaxf(bf2f(v[i]) * sc[i] + sh[i], 0.f);
    }
    u16x8 o;
#pragma unroll
    for (int i = 0; i < 8; i++) o[i] = f2bf(acc[i]);
    z[((size_t)n << 4) + q] = o;
}

// ===== weight prep: Wt[n][k] = bf16(W[k][n]) for 8 weights in one launch =====
struct WtJob  { const float* src; unsigned short* dst; int K; int N; };
struct WtJobs { WtJob j[8]; };
__global__ void k_wt_cast(WtJobs jobs) {
    WtJob jb = jobs.j[blockIdx.y];
    int total = jb.K * jb.N;
    for (int i = blockIdx.x * blockDim.x + threadIdx.x; i < total; i += gridDim.x * blockDim.x) {
        int nn = i / jb.K, kk = i - nn * jb.K;
        jb.dst[i] = f2bf(jb.src[(size_t)kk * jb.N + nn]);
    }
}

// ===== MFMA bf16 GEMM: C[M,N] = A'[M,K] @ Wt[N,K]^T + bias; bf16 out =====
template <int STATS, int BNA, int TM, int TN, int BIAS2, int SPLIT>
__global__ __launch_bounds__(256) void k_mfma_gemm(const unsigned short* __restrict__ A,
                                                   const unsigned short* __restrict__ Wt,
                                                   const float* __restrict__ biasL,
                                                   const float* __restrict__ biasR,
                                                   unsigned short* __restrict__ Cout,
                                                   int M, int K, int N,
                                                   float* __restrict__ stats_sums,
                                                   const float* __restrict__ bn_sums,
                                                   const float* __restrict__ bn_g,
                                                   const float* __restrict__ bn_b) {
    constexpr int BNF = (TM == 128) ? (TN / 32) : (TN / 64);  // frags per wave (col dir)
    constexpr int BPASS = TN / 64;                            // B-tile load passes
    __shared__ unsigned short As[TM][40];
    __shared__ unsigned short Bs[TN][40];
    __shared__ float s_scale[BNA ? HID : 1], s_shift[BNA ? HID : 1];
    const int t = threadIdx.x;
    if (BNA) {
        if (t < HID) {
            float mean = bn_sums[t] / M;
            float istd = rsqrtf(bn_sums[HID + t] / M - mean * mean + EPSV);
            float s = istd * bn_g[t];
            s_scale[t] = s;
            s_shift[t] = bn_b[t] - mean * s;
        }
        __syncthreads();
    }
    const int wave = t >> 6, lane = t & 63;
    const int row0 = blockIdx.y * TM, col0 = blockIdx.x * TN;
    const int wm = (TM == 128) ? ((wave & 1) << 6) : 0;
    const int wn = (TM == 128) ? ((wave >> 1) << 6)
                               : ((TN == 128) ? (wave << 5) : (wave << 4));
    const int lm = lane & 15, lk = (lane >> 4) << 3;
    constexpr int APASS = TM / 64;
    f32x4 acc[4][BNF] = {};
    for (int k0 = 0; k0 < K; k0 += 32) {
        u16x8 av[APASS], wv[BPASS];
#pragma unroll
        for (int i = 0; i < APASS; i++) {
            int c = t + (i << 8);
            int r = c >> 2, ko = (c & 3) << 3;
            u16x8 zv = {};
            int gr = row0 + r;
            av[i] = (gr < M) ? *(const u16x8*)&A[(size_t)gr * K + k0 + ko] : zv;
            if (BNA) {
#pragma unroll
                for (int j = 0; j < 8; j++) {
                    int kc = k0 + ko + j;
                    float v = fmaxf(bf2f(av[i][j]) * s_scale[kc] + s_shift[kc], 0.f);
                    av[i][j] = f2bf(v);
                }
            }
        }
#pragma unroll
        for (int i = 0; i < BPASS; i++) {
            int c = t + (i << 8);
            int r = c >> 2, ko = (c & 3) << 3;
            wv[i] = *(const u16x8*)&Wt[(size_t)(col0 + r) * K + k0 + ko];
        }
        __syncthreads();
#pragma unroll
        for (int i = 0; i < APASS; i++) {
            int c = t + (i << 8);
            int r = c >> 2, ko = (c & 3) << 3;
            *(u16x8*)&As[r][ko] = av[i];
        }
#pragma unroll
        for (int i = 0; i < BPASS; i++) {
            int c = t + (i << 8);
            int r = c >> 2, ko = (c & 3) << 3;
            *(u16x8*)&Bs[r][ko] = wv[i];
        }
        __syncthreads();
        bf16x8 af[4], bfm[BNF];
#pragma unroll
        for (int i = 0; i < 4; i++) af[i]  = *(const bf16x8*)&As[wm + (i << 4) + lm][lk];
#pragma unroll
        for (int j = 0; j < BNF; j++) bfm[j] = *(const bf16x8*)&Bs[wn + (j << 4) + lm][lk];
#pragma unroll
        for (int i = 0; i < 4; i++)
#pragma unroll
            for (int j = 0; j < BNF; j++)
                acc[i][j] = __builtin_amdgcn_mfma_f32_16x16x32_bf16(af[i], bfm[j], acc[i][j], 0, 0, 0);
    }
    const int lr4 = (lane >> 4) << 2;
    float s1[BNF], s2[BNF];
#pragma unroll
    for (int j = 0; j < BNF; j++) { s1[j] = 0.f; s2[j] = 0.f; }
#pragma unroll
    for (int j = 0; j < BNF; j++) {
        int col = col0 + wn + (j << 4) + lm;
        float bv = BIAS2 ? ((col < 256) ? biasL[col] : biasR[col - 256]) : biasL[col];
        unsigned short* dstp;
        int cl;
        if (SPLIT) {
            if (col < 256) { dstp = Cout; cl = col; }
            else { dstp = Cout + (size_t)N_NODES * 256; cl = col - 256; }
        } else { dstp = Cout; cl = col; }
#pragma unroll
        for (int i = 0; i < 4; i++) {
#pragma unroll
            for (int r = 0; r < 4; r++) {
                int row = row0 + wm + (i << 4) + lr4 + r;
                if (row < M) {
                    float v = acc[i][j][r] + bv;
                    if (SPLIT) dstp[(size_t)row * 256 + cl] = f2bf(v);
                    else       dstp[(size_t)row * N + cl]   = f2bf(v);
                    if (STATS) { s1[j] += v; s2[j] += v * v; }
                }
            }
        }
    }
    if (STATS) {
#pragma unroll
        for (int j = 0; j < BNF; j++) {
            s1[j] += __shfl_xor(s1[j], 16, 64); s1[j] += __shfl_xor(s1[j], 32, 64);
            s2[j] += __shfl_xor(s2[j], 16, 64); s2[j] += __shfl_xor(s2[j], 32, 64);
        }
        if ((lane >> 4) == 0) {
#pragma unroll
            for (int j = 0; j < BNF; j++) {
                int col = col0 + wn + (j << 4) + lm;
                atomicAdd(&stats_sums[col], s1[j]);
                atomicAdd(&stats_sums[HID + col], s2[j]);
            }
        }
    }
}

// ========== fused ATTConv (GATv2): half-wave edge-paired online softmax ==========
// R9: byte-for-byte revert of the att kernel to the R6 version (best measured:
// <=43.5us, VGPR 56, LDS 6144, 0 bank conflicts). R7/R8 tail restructurings both
// regressed (VGPR bloat / LDS-scratch spill + bank conflicts). 16-wide main loop,
// 8-edge step, serial pair remainder.
#define ATT_CAP 192
#define LOG2E   1.4426950408889634f
#define DTHR    11.0f

__device__ __forceinline__ float att_logit8(u16x8 uv, const float* xr8, const float* at8, float* x8) {
    float tl = 0.f;
#pragma unroll
    for (int i = 0; i < 8; i++) {
        x8[i] = bf2f(uv[i]);
        float v = x8[i] + xr8[i];
        v = fmaxf(v, 0.2f * v);     // leaky_relu(v,0.2): max(v,0.2v) exact for all v
        tl = fmaf(at8[i], v, tl);
    }
    return tl;
}

template <int CTRL>
__device__ __forceinline__ float dpp_add(float x) {
    int y = __builtin_amdgcn_update_dpp(0, __float_as_int(x), CTRL, 0xF, 0xF, true);
    return x + __int_as_float(y);
}

// sum across each 16-lane group, all lanes get result; pure VALU (no LDS)
__device__ __forceinline__ float red16(float tl) {
    tl = dpp_add<0xB1>(tl);    // quad_perm [1,0,3,2]  (xor 1)
    tl = dpp_add<0x4E>(tl);    // quad_perm [2,3,0,1]  (xor 2)
    tl = dpp_add<0x124>(tl);   // row_ror:4 (quad-sum rotate)
    tl = dpp_add<0x128>(tl);   // row_ror:8
    return tl;
}

// one 8-edge group (4 edges per half-wave): logits + reduce + deferred-max online update
template <int WITH_ALPHA>
__device__ __forceinline__ void att_group4(const u16x8* uv, int ebase, int p0,
                                           int half, int j, int h,
                                           const float* xr8, const float* at8,
                                           float& m, float& ssum, float* acc,
                                           float (*slg)[2]) {
    float x8[4][8], tl[4];
#pragma unroll
    for (int g = 0; g < 4; g++) tl[g] = att_logit8(uv[g], xr8, at8, x8[g]);
#pragma unroll
    for (int g = 0; g < 4; g++) tl[g] = red16(tl[g]);
    if (WITH_ALPHA && (j & 15) == 0) {
#pragma unroll
        for (int g = 0; g < 4; g++) {
            int idx = ebase + (g << 1) + half - p0;
            if (idx < ATT_CAP) slg[idx][h] = tl[g];
        }
    }
    float pm = fmaxf(fmaxf(tl[0], tl[1]), fmaxf(tl[2], tl[3]));
    if (__builtin_expect(!__all(pm <= m + DTHR), 0)) {
        // rare rescale path: full sequential online update
#pragma unroll
        for (int g = 0; g < 4; g++) {
            float mn = fmaxf(m, tl[g]);
            float sc = fexp2(m - mn);
            float w  = fexp2(tl[g] - mn);
            ssum = ssum * sc + w;
#pragma unroll
            for (int i = 0; i < 8; i++) acc[i] = acc[i] * sc + w * x8[g][i];
            m = mn;
        }
    } else {
        float w0 = fexp2(tl[0] - m), w1 = fexp2(tl[1] - m);
        float w2 = fexp2(tl[2] - m), w3 = fexp2(tl[3] - m);
        ssum += (w0 + w1) + (w2 + w3);
#pragma unroll
        for (int i = 0; i < 8; i++)
            acc[i] += (w0 * x8[0][i] + w1 * x8[1][i]) + (w2 * x8[2][i] + w3 * x8[3][i]);
    }
}

template <int CONCAT, int WITH_ALPHA>
__global__ __launch_bounds__(256) void k_att_fused(const u16x8* __restrict__ XL,
                                                   const u16x8* __restrict__ XR,
                                                   const int* __restrict__ rowptr,
                                                   const int* __restrict__ plist,
                                                   const int* __restrict__ srclist,
                                                   const float* __restrict__ att,
                                                   const float* __restrict__ bias,
                                                   void* __restrict__ outp,
                                                   float* __restrict__ alpha_out) {
    __shared__ float s_lg[WITH_ALPHA ? 4 : 1][WITH_ALPHA ? ATT_CAP : 1][2];
    const int t = threadIdx.x;
    const int wave = t >> 6, l = t & 63;
    const int n = blockIdx.x * 4 + wave;   // N_NODES % 4 == 0
    const int half = l >> 5;               // which edge of the pair this lane serves
    const int j = l & 31;                  // channel group: channels 8j..8j+7
    const int h = j >> 4;                  // head

    // xr slice (8 channels) + att row (pre-scaled by log2e -> logits in log2 domain)
    u16x8 ur = XR[((size_t)n << 5) + j];
    float xr8[8];
#pragma unroll
    for (int i = 0; i < 8; i++) xr8[i] = bf2f(ur[i]);
    const float* ap = &att[h * HID + ((j & 15) << 3)];
    float at8[8];
#pragma unroll
    for (int i = 0; i < 8; i++) at8[i] = ap[i] * LOG2E;

    const int p0 = rowptr[n], p1 = rowptr[n + 1];
    const int* PL = WITH_ALPHA ? srclist : plist;
    const int deg = p1 - p0;
    // idx preload: lane l holds src of edge l (first 64 edges), fetched via bpermute
    int idxreg = (deg > 0) ? PL[p0 + ((l < deg) ? l : (deg - 1))] : 0;

    float m = -1e30f, ssum = 0.f;      // finite sentinel: avoids inf-inf NaNs
    float acc[8] = {};
    float (*slg)[2] = WITH_ALPHA ? s_lg[wave] : nullptr;

    int p = p0;
    // ---- wide main loop: 16 edges (8 row loads in flight) per iteration ----
    for (; p + 16 <= p1; p += 16) {
        int rb = p - p0;
        int sA[4], sB[4];
        if (rb + 16 <= 64) {
#pragma unroll
            for (int g = 0; g < 4; g++)
                sA[g] = __builtin_amdgcn_ds_bpermute((rb + (g << 1) + half) << 2, idxreg);
#pragma unroll
            for (int g = 0; g < 4; g++)
                sB[g] = __builtin_amdgcn_ds_bpermute((rb + 8 + (g << 1) + half) << 2, idxreg);
        } else {
#pragma unroll
            for (int g = 0; g < 4; g++) sA[g] = PL[p + (g << 1) + half];
#pragma unroll
            for (int g = 0; g < 4; g++) sB[g] = PL[p + 8 + (g << 1) + half];
        }
        u16x8 uvA[4], uvB[4];
#pragma unroll
        for (int g = 0; g < 4; g++) uvA[g] = XL[((size_t)sA[g] << 5) + j];
#pragma unroll
        for (int g = 0; g < 4; g++) uvB[g] = XL[((size_t)sB[g] << 5) + j];
        att_group4<WITH_ALPHA>(uvA, p,     p0, half, j, h, xr8, at8, m, ssum, acc, slg);
        att_group4<WITH_ALPHA>(uvB, p + 8, p0, half, j, h, xr8, at8, m, ssum, acc, slg);
    }
    // ---- 8-edge step ----
    for (; p + 8 <= p1; p += 8) {
        int rb = p - p0;
        int s4[4];
        if (rb + 8 <= 64) {
#pragma unroll
            for (int g = 0; g < 4; g++)
                s4[g] = __builtin_amdgcn_ds_bpermute((rb + (g << 1) + half) << 2, idxreg);
        } else {
#pragma unroll
            for (int g = 0; g < 4; g++) s4[g] = PL[p + (g << 1) + half];
        }
        u16x8 uv[4];
#pragma unroll
        for (int g = 0; g < 4; g++) uv[g] = XL[((size_t)s4[g] << 5) + j];
        att_group4<WITH_ALPHA>(uv, p, p0, half, j, h, xr8, at8, m, ssum, acc, slg);
    }
    // ---- pair remainder (up to 3 iterations; last pair may be half-valid) ----
    for (; p < p1; p += 2) {
        const bool v1 = (p + 1 < p1);
        int er = (half && v1) ? (p + 1) : p;
        int src;
        if (p - p0 + 2 <= 64) src = __builtin_amdgcn_ds_bpermute((er - p0) << 2, idxreg);
        else src = PL[er];
        u16x8 uv = XL[((size_t)src << 5) + j];
        float x8[8], tl;
        tl = att_logit8(uv, xr8, at8, x8);
        tl = red16(tl);
        float vm = (half && !v1) ? 0.f : 1.f;
        if (vm == 0.f) tl = -1e30f;
        if (WITH_ALPHA && (j & 15) == 0 && vm != 0.f) {
            int idx = p + half - p0;
            if (idx < ATT_CAP) s_lg[wave][idx][h] = tl;
        }
        if (__builtin_expect(!__all(tl <= m + DTHR), 0)) {
            float mn = fmaxf(m, tl);
            float sc = fexp2(m - mn);
            float w  = fexp2(tl - mn) * vm;
            ssum = ssum * sc + w;
#pragma unroll
            for (int i = 0; i < 8; i++) acc[i] = acc[i] * sc + w * x8[i];
            m = mn;
        } else {
            float w = fexp2(tl - m) * vm;
            ssum += w;
#pragma unroll
            for (int i = 0; i < 8; i++) acc[i] += w * x8[i];
        }
    }

    // ---- merge the two half-wave softmax states (symmetric: both halves get result) ----
    float m_o = __shfl_xor(m, 32, 64);
    float mf  = fmaxf(m, m_o);
    float sA  = fexp2(m - mf);             // m,mf finite -> 0-edge case gives sA=1
    float ssA = ssum * sA;
    float ssum_f = ssA + __shfl_xor(ssA, 32, 64);
    float accf[8];
#pragma unroll
    for (int i = 0; i < 8; i++) {
        float a = acc[i] * sA;
        accf[i] = a + __shfl_xor(a, 32, 64);
    }
    float inv = 1.f / (ssum_f + 1e-16f);

    // ---- alpha output (att2): parallel from LDS cache ----
    if (WITH_ALPHA) {
        float m_oh   = __shfl_xor(mf, 16, 64);
        float inv_oh = __shfl_xor(inv, 16, 64);
        float m2[2], i2[2];
        m2[h] = mf;  m2[1 - h] = m_oh;
        i2[h] = inv; i2[1 - h] = inv_oh;
        int cnt = p1 - p0;
        int ccnt = (cnt < ATT_CAP) ? cnt : ATT_CAP;
        for (int i = l; i < ccnt * 2; i += 64) {
            int idx = i >> 1, hh = i & 1;
            float a = fexp2(s_lg[wave][idx][hh] - m2[hh]) * i2[hh];
            alpha_out[plist[p0 + idx] * HEADS + hh] = a;
        }
        // overflow fallback (deg > ATT_CAP): serial recompute (practically never taken)
        for (int pp = p0 + ATT_CAP; pp < p1; pp++) {
            int src = PL[pp];
            u16x8 uv = XL[((size_t)src << 5) + j];
            float x8[8], tl;
            tl = att_logit8(uv, xr8, at8, x8);
            tl = red16(tl);
            if ((j & 15) == 0 && half == 0)
                alpha_out[plist[pp] * HEADS + h] = fexp2(tl - mf) * inv;
        }
    }

    // ---- epilogue ----
    if (CONCAT) {
        if (half == 0) {
            const float* bp = &bias[j << 3];
            u16x8 o;
#pragma unroll
            for (int i = 0; i < 8; i++) o[i] = f2bf(fmaxf(accf[i] * inv + bp[i], 0.f));
            ((u16x8*)outp)[((size_t)n << 5) + j] = o;
        }
    } else {
        float om[8];
#pragma unroll
        for (int i = 0; i < 8; i++) {
            float v = accf[i] * inv;
            om[i] = 0.5f * (v + __shfl_xor(v, 16, 64));
        }
        if (half == 0 && h == 0) {
            const float* bp = &bias[j << 3];
            float4 o0, o1;
            o0.x = fmaxf(om[0] + bp[0], 0.f); o0.y = fmaxf(om[1] + bp[1], 0.f);
            o0.z = fmaxf(om[2] + bp[2], 0.f); o0.w = fmaxf(om[3] + bp[3], 0.f);
            o1.x = fmaxf(om[4] + bp[4], 0.f); o1.y = fmaxf(om[5] + bp[5], 0.f);
            o1.z = fmaxf(om[6] + bp[6], 0.f); o1.w = fmaxf(om[7] + bp[7], 0.f);
            ((float4*)outp)[((size_t)n << 5) + (j << 1)]     = o0;
            ((float4*)outp)[((size_t)n << 5) + (j << 1) + 1] = o1;
        }
    }
}

// ================= pooling over sorted batch_index (node-parallel) =================
template <int C>
__global__ __launch_bounds__(256) void k_pool_atomic(const float* __restrict__ X,
                                                     const int* __restrict__ batch,
                                                     float* __restrict__ pool, int npb) {
    const int RP = 256 / C;
    int c = threadIdx.x & (C - 1);
    int rofs = threadIdx.x / C;
    int i0 = blockIdx.x * npb;
    int i1 = min(i0 + npb, N_NODES);
    float acc = 0.f;
    int gcur = -1;
    for (int i = i0 + rofs; i < i1; i += RP) {
        int g = batch[i];
        if (g != gcur) {
            if (gcur >= 0) atomicAdd(&pool[gcur * C + c], acc);
            acc = 0.f; gcur = g;
        }
        acc += X[(size_t)i * C + c];
    }
    if (gcur >= 0) atomicAdd(&pool[gcur * C + c], acc);
}

// ================= final prediction head =================
__global__ void k_head(const float* __restrict__ pool0, const float* __restrict__ poolL,
                       const float* __restrict__ p0w, const float* __restrict__ p0b,
                       const float* __restrict__ pLw, const float* __restrict__ pLb,
                       const float* __restrict__ ow, const float* __restrict__ ob,
                       float* __restrict__ outputs) {
    int g = blockIdx.x;
    int m = threadIdx.x;
    __shared__ float sh[MIDD];
    if (m < MIDD) {
        float s = p0b[m] + pLb[m];
        for (int k = 0; k < F_INN; k++) s += pool0[g * F_INN + k] * p0w[k * MIDD + m];
        for (int k = 0; k < HID; k++)  s += poolL[g * HID + k] * pLw[k * MIDD + m];
        sh[m] = fmaxf(s, 0.f);
    }
    __syncthreads();
    if (m == 0) {
        float s = ob[0];
        for (int k = 0; k < MIDD; k++) s += sh[k] * ow[k];
        outputs[g] = s;
    }
}

extern "C" void kernel_launch(void* const* d_in, const int* in_sizes, int n_in,
                              void* d_out, int out_size, void* d_ws, size_t ws_size,
                              hipStream_t stream) {
    // ---- inputs ----
    const float* x      = (const float*)d_in[0];
    const int*   ei     = (const int*)d_in[1];
    const int*   aei    = (const int*)d_in[2];
    const int*   batch  = (const int*)d_in[3];
    const float* g0_w1  = (const float*)d_in[4];
    const float* g0_b1  = (const float*)d_in[5];
    const float* g0_bng = (const float*)d_in[6];
    const float* g0_bnb = (const float*)d_in[7];
    const float* g0_w2  = (const float*)d_in[8];
    const float* g0_b2  = (const float*)d_in[9];
    const float* g1_w1  = (const float*)d_in[10];
    const float* g1_b1  = (const float*)d_in[11];
    const float* g1_bng = (const float*)d_in[12];
    const float* g1_bnb = (const float*)d_in[13];
    const float* g1_w2  = (const float*)d_in[14];
    const float* g1_b2  = (const float*)d_in[15];
    const float* bn0_g  = (const float*)d_in[16];
    const float* bn0_b  = (const float*)d_in[17];
    const float* bn1_g  = (const float*)d_in[18];
    const float* bn1_b  = (const float*)d_in[19];
    const float* a1_wl  = (const float*)d_in[20];
    const float* a1_bl  = (const float*)d_in[21];
    const float* a1_wr  = (const float*)d_in[22];
    const float* a1_br  = (const float*)d_in[23];
    const float* a1_att = (const float*)d_in[24];
    const float* a1_bias= (const float*)d_in[25];
    const float* a2_wl  = (const float*)d_in[26];
    const float* a2_bl  = (const float*)d_in[27];
    const float* a2_wr  = (const float*)d_in[28];
    const float* a2_br  = (const float*)d_in[29];
    const float* a2_att = (const float*)d_in[30];
    const float* a2_bias= (const float*)d_in[31];
    const float* p0w    = (const float*)d_in[32];
    const float* p0b    = (const float*)d_in[33];
    const float* pLw    = (const float*)d_in[34];
    const float* pLb    = (const float*)d_in[35];
    const float* ow     = (const float*)d_in[36];
    const float* ob     = (const float*)d_in[37];

    // ---- outputs ----
    float* out_head  = (float*)d_out;
    float* atten_out = out_head + G_GR;
    float* alpha_out = atten_out + (size_t)N_NODES * HID;

    // ---- workspace ----
    float* ws = (float*)d_ws;
    float* sums4 = ws;                                 // 4*256 (s0|s1|s2|s3)
    float* pool0 = sums4 + 4 * 256;                    // G*64
    float* poolL = pool0 + G_GR * F_INN;               // G*128
    int*   btot  = (int*)(poolL + G_GR * HID);         // 3*NBUK (zeroed)
    const size_t zero_bytes = (4 * 256 + G_GR * F_INN + G_GR * HID + 3 * NBUK) * 4;

    int* ip = btot + 3 * NBUK;
    int* bstart = ip; ip += 3 * (NBUK + 1);
    int* bcur   = ip; ip += 3 * NBUK;
    int* rowptr[3]; int* payload[3];
    for (int c = 0; c < 3; c++) {
        rowptr[c]  = ip; ip += N_NODES + 1;
        payload[c] = ip; ip += E_EDGES;
    }
    int* tmp3 = ip; ip += 3 * E_EDGES;                 // [3][E] packed int
    int* srclist = tmp3;                               // reuse: tmp3 dead after bucketB
    const size_t NB = (size_t)N_NODES * HC;
    unsigned short* B1 = (unsigned short*)ip;          // [N,HC] bf16
    unsigned short* B2 = B1 + NB;                      // [N,HC] bf16
    unsigned short* Qb = B2 + NB;                      // XL [N,256] | XR [N,256] bf16
    unsigned short* g0w1t = Qb + 2 * NB;
    unsigned short* g0w2t = g0w1t + 128 * 64;
    unsigned short* g1w1t = g0w2t + 128 * 128;
    unsigned short* g1w2t = g1w1t + 128 * 128;
    unsigned short* a1wlt = g1w2t + 128 * 128;         // [256,128]
    unsigned short* a1wrt = a1wlt + 256 * 128;         // contiguous -> [512,128]
    unsigned short* a2wlt = a1wrt + 256 * 128;         // [256,256]
    unsigned short* a2wrt = a2wlt + 256 * 256;         // contiguous -> [512,256]

    unsigned short* XLb = Qb;                          // xl rows (gathered per edge)
    unsigned short* XRb = Qb + (size_t)N_NODES * 256;  // xr rows (read once per node)

    const int* e_row = ei;
    const int* e_col = ei + E_EDGES;
    const int* a_src = aei;
    const int* a_dst = aei + E_EDGES;

    const int TB = 256;
#define GRID1(n) dim3(CDIV((n), TB))

    // ===== weight transpose+cast =====
    {
        WtJobs jobs;
        jobs.j[0] = {g0_w1, g0w1t, F_INN, HID};
        jobs.j[1] = {g0_w2, g0w2t, HID,   HID};
        jobs.j[2] = {g1_w1, g1w1t, HID,   HID};
        jobs.j[3] = {g1_w2, g1w2t, HID,   HID};
        jobs.j[4] = {a1_wl, a1wlt, HID,   HC};
        jobs.j[5] = {a1_wr, a1wrt, HID,   HC};
        jobs.j[6] = {a2_wl, a2wlt, HC,    HC};
        jobs.j[7] = {a2_wr, a2wrt, HC,    HC};
        k_wt_cast<<<dim3(32, 8), TB, 0, stream>>>(jobs);
    }

    // ===== zero sums/pools/btot in one shot; build 3 CSRs (bucket-granular) =====
    (void)hipMemsetAsync(sums4, 0, zero_bytes, stream);
    {
        Csr3 c;
        c.key[0] = e_row; c.other[0] = e_col;
        c.key[1] = e_col; c.other[1] = e_row;
        c.key[2] = a_dst; c.other[2] = a_src;
        c.btot = btot; c.bstart = bstart; c.bcur = bcur; c.tmp = tmp3;
        for (int i = 0; i < 3; i++) { c.rowptr[i] = rowptr[i]; c.out[i] = payload[i]; }
        k_bhist<<<dim3(CDIV(E_EDGES, 4096), 3), TB, 0, stream>>>(c);
        k_bscan<<<dim3(1), TB, 0, stream>>>(c);
        k_bucketA<<<dim3(CDIV(E_EDGES, 4096), 3), TB, 0, stream>>>(c);
        k_bucketB<<<dim3(NBUK, 3), TB, 0, stream>>>(c);
    }

    // ===== merged front: GANConv0 gather | att2 srclist | pool0 (one dispatch) =====
    {
        FrontArgs fa;
        fa.x = (const float4*)x; fa.rowptr0 = rowptr[0]; fa.pay0 = payload[0];
        fa.z = B1;
        fa.pay2 = payload[2]; fa.asrc = a_src; fa.srclist = srclist;
        fa.batch = batch; fa.pool0 = pool0;
        k_front<<<dim3(2813), TB, 0, stream>>>(fa);
    }

    const dim3 gemm_g1(2, CDIV(N_NODES, 64));    // N=128 as 2x64-col tiles (626 blocks)
    const dim3 gemm_gq(4, CDIV(N_NODES, 128));   // N=512, TM=128 (628 blocks)
    const float* NOF = nullptr;

    // ===== GANConv 0 (ping-pong B1/B2 as [N,128]) =====
    k_mfma_gemm<1, 0, 64, 64, 0, 0><<<gemm_g1, TB, 0, stream>>>(B1, g0w1t, g0_b1, NOF, B2, N_NODES, F_INN, HID,
                                                                sums4 + 0, NOF, NOF, NOF);
    k_mfma_gemm<1, 1, 64, 64, 0, 0><<<gemm_g1, TB, 0, stream>>>(B2, g0w2t, g0_b2, NOF, B1, N_NODES, HID, HID,
                                                                sums4 + 256, sums4 + 0, g0_bng, g0_bnb);
    // raw2 (pre-bn0) in B1

    // ===== GANConv 1 =====
    k_gather_bn<<<GRID1(N_NODES * 16), TB, 0, stream>>>((const u16x8*)B1, rowptr[0], payload[0],
                                                        sums4 + 256, bn0_g, bn0_b, (u16x8*)B2);
    k_mfma_gemm<1, 0, 64, 64, 0, 0><<<gemm_g1, TB, 0, stream>>>(B2, g1w1t, g1_b1, NOF, B1, N_NODES, HID, HID,
                                                                sums4 + 512, NOF, NOF, NOF);
    k_mfma_gemm<1, 1, 64, 64, 0, 0><<<gemm_g1, TB, 0, stream>>>(B1, g1w2t, g1_b2, NOF, B2, N_NODES, HID, HID,
                                                                sums4 + 768, sums4 + 512, g1_bng, g1_bnb);
    // raw4 (pre-bn1 = h2 raw) in B2

    // ===== ATTConv 1 (dst=e_col, concat=True): merged wl|wr GEMM -> XL|XR =====
    k_mfma_gemm<0, 1, 128, 128, 1, 1><<<gemm_gq, TB, 0, stream>>>(B2, a1wlt, a1_bl, a1_br, XLb, N_NODES, HID, 512,
                                                                  nullptr, sums4 + 768, bn1_g, bn1_b);
    k_att_fused<1, 0><<<dim3(N_NODES / 4), TB, 0, stream>>>(
        (const u16x8*)XLb, (const u16x8*)XRb, rowptr[1], payload[1], nullptr,
        a1_att, a1_bias, (void*)B1, nullptr);
    // emb bf16 in B1 [N,HC]

    // ===== ATTConv 2 (dst=a_dst, concat=False): merged GEMM K=256 -> XL|XR =====
    k_mfma_gemm<0, 0, 128, 128, 1, 1><<<gemm_gq, TB, 0, stream>>>(B1, a2wlt, a2_bl, a2_br, XLb, N_NODES, HC, 512,
                                                                  nullptr, NOF, NOF, NOF);
    k_att_fused<0, 1><<<dim3(N_NODES / 4), TB, 0, stream>>>(
        (const u16x8*)XLb, (const u16x8*)XRb, rowptr[2], payload[2], srclist,
        a2_att, a2_bias, (void*)atten_out, alpha_out);

    // ===== pooling + head =====
    k_pool_atomic<HID><<<dim3(CDIV(N_NODES, 64)), TB, 0, stream>>>(atten_out, batch, poolL, 64);
    k_head<<<dim3(G_GR), 64, 0, stream>>>(pool0, poolL, p0w, p0b, pLw, pLb, ow, ob, out_head);
}